// Round 15
// baseline (261.739 us; speedup 1.0000x reference)
//
#include <hip/hip_runtime.h>
#include <hip/hip_bf16.h>

#define DEV static __device__ __forceinline__

constexpr int BB = 4;        // batches
constexpr int TT = 12;       // timesteps
constexpr int NN = 10000;    // nodes per batch
constexpr int FD = 16;       // input features (8+8)
constexpr int HD = 128;      // hidden
constexpr int NH = 4;        // attn heads
constexpr int DH = 32;       // head dim
constexpr int FF = 256;      // ffn hidden
constexpr int GO = 64;       // gat2 out
constexpr int HR = 24;       // horizon
constexpr int EE = 160000;   // edges per batch
constexpr int MM = BB * NN;  // total nodes

typedef unsigned short bvec8 __attribute__((ext_vector_type(8)));
typedef unsigned short usvec4 __attribute__((ext_vector_type(4)));
typedef float fvec4 __attribute__((ext_vector_type(4)));
typedef short bs8 __attribute__((ext_vector_type(8)));      // MFMA bf16 frag (4 VGPR)

DEV float lrelu(float x) { return x >= 0.f ? x : 0.2f * x; }

DEV float b2f(unsigned short u) {
  union { unsigned int i; float f; } x; x.i = ((unsigned int)u) << 16; return x.f;
}
DEV unsigned short f2b(float f) {
  union { float f; unsigned int i; } x; x.f = f;
  unsigned int r = x.i + 0x7FFFu + ((x.i >> 16) & 1u);
  return (unsigned short)(r >> 16);
}
DEV void up2(unsigned int u, float& lo, float& hi) {
  union { unsigned int i; float f; } a, b;
  a.i = u << 16; b.i = u & 0xFFFF0000u;
  lo = a.f; hi = b.f;
}

DEV fvec4 mfma16(bs8 a, bs8 b, fvec4 c) {
  return __builtin_amdgcn_mfma_f32_16x16x32_bf16(a, b, c, 0, 0, 0);
}

// ---------------- prep: fold + re-layout ALL transformer weights (fp32 in) --
// Also zeroes the CSR histogram (tail blocks).
// MFMA B-fragment order: frag idx = ((nt*nK + kk)*64 + lane), element e:
//   B[k][n] with k = kk*32 + (lane>>4)*8 + e, n = nt*16 + (lane&15).
__global__ __launch_bounds__(256) void k_prep(
    const float* __restrict__ Wq, const float* __restrict__ Wk,
    const float* __restrict__ Wv, const float* __restrict__ Wo,
    const float* __restrict__ encW, const float* __restrict__ encB,
    const float* __restrict__ W1, const float* __restrict__ fb1,
    const float* __restrict__ W2, const float* __restrict__ fb2,
    const float* __restrict__ l1g, const float* __restrict__ l1b,
    const float* __restrict__ l2g, const float* __restrict__ l2b,
    const float* __restrict__ gW1,
    unsigned short* __restrict__ Mu, unsigned short* __restrict__ Pw,
    unsigned short* __restrict__ W1F, unsigned short* __restrict__ W2F,
    unsigned short* __restrict__ encWF, unsigned short* __restrict__ gW1F,
    float* __restrict__ encBf, float* __restrict__ fb1f, float* __restrict__ fb2f,
    float* __restrict__ l1gf, float* __restrict__ l1bf,
    float* __restrict__ l2gf, float* __restrict__ l2bf,
    int* __restrict__ cnt)
{
  int idx = blockIdx.x * 256 + threadIdx.x;      // 892*256 = 228352
  if (idx < 65536) {
    int e = idx & 7, lane = (idx >> 3) & 63, kk = (idx >> 9) & 3, nt = idx >> 11;
    int i = kk*32 + (lane >> 4)*8 + e;
    int q = nt*16 + (lane & 15);
    int h = q >> 7, c = q & 127;
    float a = 0.f;
    #pragma unroll 8
    for (int d = 0; d < DH; ++d)
      a += Wq[i*HD + h*DH + d] * Wk[c*HD + h*DH + d];
    Mu[idx] = f2b(a);
  } else if (idx < 131072) {
    int g2 = idx - 65536;
    int e = g2 & 7, lane = (g2 >> 3) & 63, kk = (g2 >> 9) & 15, nt = g2 >> 13;
    int q = kk*32 + (lane >> 4)*8 + e;
    int j = nt*16 + (lane & 15);
    int h = q >> 7, i = q & 127;
    float a = 0.f;
    #pragma unroll 8
    for (int d = 0; d < DH; ++d)
      a += Wv[i*HD + h*DH + d] * Wo[(h*DH + d)*HD + j];
    Pw[g2] = f2b(a);
  } else if (idx < 163840) {
    int g = idx - 131072;
    int e = g & 7, lane = (g >> 3) & 63, kk = (g >> 9) & 3, nt = g >> 11;
    int k = kk*32 + (lane >> 4)*8 + e;
    int n = nt*16 + (lane & 15);
    W1F[g] = f2b(W1[k*FF + n]);
  } else if (idx < 196608) {
    int g = idx - 163840;
    int e = g & 7, lane = (g >> 3) & 63, kk = (g >> 9) & 7, nt = g >> 12;
    int k = kk*32 + (lane >> 4)*8 + e;
    int n = nt*16 + (lane & 15);
    W2F[g] = f2b(W2[k*HD + n]);
  } else if (idx < 200704) {
    int g = idx - 196608;
    int e = g & 7, lane = (g >> 3) & 63, nt = g >> 9;
    int k = (lane >> 4)*8 + e;
    int n = nt*16 + (lane & 15);
    encWF[g] = (k < FD) ? f2b(encW[k*HD + n]) : (unsigned short)0;
  } else if (idx < 217088) {
    int g = idx - 200704;
    int e = g & 7, lane = (g >> 3) & 63, kk = (g >> 9) & 3, nt = g >> 11;
    int k = kk*32 + (lane >> 4)*8 + e;
    int n = nt*16 + (lane & 15);
    gW1F[g] = f2b(gW1[k*HD + n]);
  } else if (idx < 217216) { int t = idx - 217088; encBf[t] = encB[t]; }
  else if (idx < 217472)   { int t = idx - 217216; fb1f[t] = fb1[t]; }
  else if (idx < 217600)   { int t = idx - 217472; fb2f[t] = fb2[t]; }
  else if (idx < 217728)   { int t = idx - 217600; l1gf[t] = l1g[t]; }
  else if (idx < 217856)   { int t = idx - 217728; l1bf[t] = l1b[t]; }
  else if (idx < 217984)   { int t = idx - 217856; l2gf[t] = l2g[t]; }
  else if (idx < 218112)   { int t = idx - 217984; l2bf[t] = l2b[t]; }
  else { int t = idx - 218112; if (t < NN) cnt[t] = 0; }
}

// ---------------- fused transformer + GAT1-pre (8 nodes, 512 thr / 8 waves) -
// Same LDS (38912 B -> 4 blocks/CU) but 8 waves/block: 32 waves/CU (occupancy
// cap) and each phase's per-wave work halves -> shorter barrier chains.
// A-frag rows beyond real data feed only DISCARDED D rows (aliased).
// All A-frag row strides are 16B multiples (round-8 lesson).
__global__ __launch_bounds__(512) void k_xform(
    const float* __restrict__ xh, const float* __restrict__ xc,
    const unsigned short* __restrict__ MuF, const unsigned short* __restrict__ PwF,
    const unsigned short* __restrict__ W1F, const unsigned short* __restrict__ W2F,
    const unsigned short* __restrict__ encWF, const unsigned short* __restrict__ gW1F,
    const float* __restrict__ encBf,
    const float* __restrict__ fb1f, const float* __restrict__ fb2f,
    const float* __restrict__ l1gf, const float* __restrict__ l1bf,
    const float* __restrict__ l2gf, const float* __restrict__ l2bf,
    const float* __restrict__ asrc, const float* __restrict__ adrc,
    unsigned short* __restrict__ xl1B, float* __restrict__ s1, float* __restrict__ d1)
{
  __shared__ __align__(16) char big[26112];
  __shared__ unsigned short hlastB[8*136];     // bf16 h_last (A-frags + residual)
  __shared__ float lgaw[8][NH][TT];
  __shared__ __align__(16) char regB[8704];    // xB -> usB -> wB -> xlF

  unsigned short* hsB = (unsigned short*)big;          // [(nl*12+t)][136]
  float* r1F = (float*)big;                            // [8][132] ph6-7
  float* h1s = (float*)(big + 4224);                   // [8][132] ph7-9
  unsigned short* h1B = (unsigned short*)(big + 8448); // [8][136] ph7-8
  float* r2F = (float*)(big + 8448);                   // [8][132] ph9-10 (over h1B)
  unsigned short* f1B = (unsigned short*)(big + 12672);// [8][264] ph8-9

  unsigned short* xB  = (unsigned short*)regB;         // [96][40]  ph0-1
  unsigned short* usB = (unsigned short*)regB;         // [8*4][136] ph2-3 (bf16 u)
  unsigned short* wB  = (unsigned short*)regB;         // [8][520]  ph5-6
  float* xlF = (float*)regB;                           // [8][128]  ph11

  const int tid  = threadIdx.x;
  const int w    = tid >> 6;                   // 0..7
  const int lane = tid & 63;
  const int m0   = blockIdx.x * 8;
  const int arow = lane & 15, akg = lane >> 4;
  const int ar8  = arow & 7;                   // aliased A-row (rows 8-15 -> 0-7)

  // --- phase 0: load x -> xB bf16, rows = t*8+nl, K zero-padded 16..31 ---
  #pragma unroll
  for (int k = 0; k < 3; ++k) {
    int idx = tid + k*512;
    int f = idx & 15, rest = idx >> 4;
    int nl = rest & 7, t = rest >> 3;
    int m = m0 + nl, b = m / NN, n = m - b*NN;
    float v = (f < 8) ? xh[(((size_t)b*TT + t)*NN + n)*8 + f]
                      : xc[(((size_t)b*TT + t)*NN + n)*8 + (f - 8)];
    xB[(t*8 + nl)*40 + f] = f2b(v);
  }
  #pragma unroll
  for (int k = 0; k < 3; ++k) {
    int idx = tid + k*512;
    xB[(idx >> 4)*40 + 16 + (idx & 15)] = 0;
  }
  __syncthreads();

  // --- phase 1: encoder via MFMA; wave w owns nt = w (16 cols) ---
  {
    const bs8* ef = (const bs8*)encWF;
    bs8 b0 = ef[w*64 + lane];
    int drow = akg*4, dc = arow;
    int j0 = w*16 + dc;
    float eb0 = encBf[j0];
    fvec4 z4 = {0.f, 0.f, 0.f, 0.f};
    #pragma unroll
    for (int mt = 0; mt < 6; ++mt) {
      bs8 af = *(const bs8*)&xB[(mt*16 + arow)*40 + akg*8];
      fvec4 d0 = mfma16(af, b0, z4);
      #pragma unroll
      for (int reg = 0; reg < 4; ++reg) {
        int gr = mt*16 + drow + reg;
        int t = gr >> 3, nl = gr & 7;
        float v0 = d0[reg] + eb0;
        unsigned short s0 = f2b(v0);
        hsB[(nl*12 + t)*136 + j0] = s0;
        if (t == TT-1) hlastB[nl*136 + j0] = s0;
      }
    }
  }
  __syncthreads();                // xB dead; hlastB ready

  // --- phase 2: u = h_last @ Mu via MFMA; wave w owns nt = w*4+n4 ---
  {
    bs8 af[4];
    #pragma unroll
    for (int kk = 0; kk < 4; ++kk)
      af[kk] = *(const bs8*)&hlastB[ar8*136 + kk*32 + akg*8];
    const bs8* bp = (const bs8*)MuF;
    fvec4 acc[4];
    #pragma unroll
    for (int n4 = 0; n4 < 4; ++n4) {
      int nt = w*4 + n4;
      const bs8* bq = bp + nt*256 + lane;
      fvec4 a4 = {0.f, 0.f, 0.f, 0.f};
      #pragma unroll
      for (int kk = 0; kk < 4; ++kk)
        a4 = mfma16(af[kk], bq[kk*64], a4);
      acc[n4] = a4;
    }
    // usB overlay of xB is safe: xB last read in phase 1, barrier above.
    if (lane < 32) {
      int drow = akg*4, dc = arow;
      #pragma unroll
      for (int n4 = 0; n4 < 4; ++n4) {
        int col = (w*4 + n4)*16 + dc, hd = col >> 7, c = col & 127;
        #pragma unroll
        for (int reg = 0; reg < 4; ++reg)
          usB[((drow + reg)*4 + hd)*136 + c] = f2b(acc[n4][reg]);
      }
    }
  }
  __syncthreads();

  // --- phase 3: logits via MFMA; wave w owns node nl = w ---
  {
    int ar12 = (arow < 12) ? arow : 0;
    int nl = w;
    const unsigned short* hb = &hsB[(nl*12 + ar12)*136 + akg*8];
    const unsigned short* ub = &usB[(nl*4 + (arow & 3))*136 + akg*8];
    fvec4 a4 = {0.f, 0.f, 0.f, 0.f};
    #pragma unroll
    for (int kk = 0; kk < 4; ++kk) {
      bs8 af = *(const bs8*)&hb[kk*32];
      bs8 bf = *(const bs8*)&ub[kk*32];
      a4 = mfma16(af, bf, a4);
    }
    if (arow < 4) {               // D col = hd
      #pragma unroll
      for (int reg = 0; reg < 4; ++reg) {
        int t = akg*4 + reg;
        if (t < TT) lgaw[nl][arow][t] = a4[reg] * 0.17677669529663687f;
      }
    }
  }
  __syncthreads();

  // --- phase 4: softmax over t ---
  if (tid < 32) {
    int nl = tid >> 2, hd = tid & 3;
    float mx = -1e30f;
    #pragma unroll
    for (int t = 0; t < TT; ++t) mx = fmaxf(mx, lgaw[nl][hd][t]);
    float ex[TT], sm = 0.f;
    #pragma unroll
    for (int t = 0; t < TT; ++t) { ex[t] = expf(lgaw[nl][hd][t] - mx); sm += ex[t]; }
    float inv = 1.f / sm;
    #pragma unroll
    for (int t = 0; t < TT; ++t) lgaw[nl][hd][t] = ex[t] * inv;
  }
  __syncthreads();

  // --- phase 5: w_h = sum_t alpha*h_t -> wB bf16 (over usB) ---
  {
    int g = tid >> 7, j = tid & 127;             // g in [0,4)
    #pragma unroll
    for (int r = 0; r < 2; ++r) {
      int nl = g*2 + r;
      float wacc[NH] = {0.f, 0.f, 0.f, 0.f};
      #pragma unroll
      for (int t = 0; t < TT; ++t) {
        float hv = b2f(hsB[(nl*12 + t)*136 + j]);
        #pragma unroll
        for (int hd = 0; hd < NH; ++hd) wacc[hd] += lgaw[nl][hd][t] * hv;
      }
      #pragma unroll
      for (int hd = 0; hd < NH; ++hd) wB[nl*520 + hd*128 + j] = f2b(wacc[hd]);
    }
  }
  __syncthreads();                // hsB dead after this point

  // --- phase 6: oa = w @ Pw via MFMA; wave w owns nt = w; r1 -> r1F ---
  {
    fvec4 pacc = {0.f,0.f,0.f,0.f};
    const bs8* bq = (const bs8*)PwF + w*1024 + lane;
    #pragma unroll
    for (int kk = 0; kk < 16; ++kk) {
      bs8 af = *(const bs8*)&wB[ar8*520 + kk*32 + akg*8];
      pacc = mfma16(af, bq[kk*64], pacc);
    }
    // r1F overlays hsB: hsB last read in phase 5, barrier above.
    if (lane < 32) {
      int drow = akg*4, dc = arow;
      int c0 = w*16 + dc;
      #pragma unroll
      for (int reg = 0; reg < 4; ++reg) {
        int nd = drow + reg;
        r1F[nd*132 + c0] = b2f(hlastB[nd*136 + c0]) + pacc[reg];
      }
    }
  }
  __syncthreads();

  // --- phase 7: LN1 (node = wave, 2 cols/lane, 64-lane reduce) ---
  {
    int nd = w, l64 = lane;
    float v[2], s = 0.f, q = 0.f;
    #pragma unroll
    for (int k = 0; k < 2; ++k) {
      v[k] = r1F[nd*132 + l64 + k*64];
      s += v[k]; q += v[k]*v[k];
    }
    #pragma unroll
    for (int off = 32; off > 0; off >>= 1) { s += __shfl_xor(s, off); q += __shfl_xor(q, off); }
    float mu = s*(1.f/128.f), var = q*(1.f/128.f) - mu*mu, rs = rsqrtf(var + 1e-5f);
    #pragma unroll
    for (int k = 0; k < 2; ++k) {
      int c = l64 + k*64;
      float hv = (v[k] - mu)*rs*l1gf[c] + l1bf[c];
      h1s[nd*132 + c] = hv;
      h1B[nd*136 + c] = f2b(hv);
    }
  }
  __syncthreads();

  // --- phase 8: FFN1 via MFMA; wave w owns nt = w*2+n2 ---
  {
    bs8 af[4];
    #pragma unroll
    for (int kk = 0; kk < 4; ++kk)
      af[kk] = *(const bs8*)&h1B[ar8*136 + kk*32 + akg*8];
    const bs8* bp = (const bs8*)W1F;
    #pragma unroll
    for (int n2 = 0; n2 < 2; ++n2) {
      int nt = w*2 + n2;
      const bs8* bq = bp + nt*256 + lane;
      fvec4 a4 = {0.f, 0.f, 0.f, 0.f};
      #pragma unroll
      for (int kk = 0; kk < 4; ++kk)
        a4 = mfma16(af[kk], bq[kk*64], a4);
      if (lane < 32) {
        int drow = akg*4, dc = arow;
        int n = nt*16 + dc;
        float bias = fb1f[n];
        #pragma unroll
        for (int reg = 0; reg < 4; ++reg)
          f1B[(drow + reg)*264 + n] = f2b(fmaxf(a4[reg] + bias, 0.f));
      }
    }
  }
  __syncthreads();

  // --- phase 9: FFN2 via MFMA; wave w owns nt = w; + residual -> r2F ---
  {
    const bs8* bq = (const bs8*)W2F + w*512 + lane;
    fvec4 a4 = {0.f, 0.f, 0.f, 0.f};
    #pragma unroll
    for (int kk = 0; kk < 8; ++kk) {
      bs8 af = *(const bs8*)&f1B[ar8*264 + kk*32 + akg*8];
      a4 = mfma16(af, bq[kk*64], a4);
    }
    if (lane < 32) {
      int drow = akg*4, dc = arow;
      int c = w*16 + dc;
      float fb2v = fb2f[c];
      #pragma unroll
      for (int reg = 0; reg < 4; ++reg) {
        int nd = drow + reg;
        r2F[nd*132 + c] = h1s[nd*132 + c] + fb2v + a4[reg];
      }
    }
  }
  __syncthreads();

  // --- phase 10: LN2 -> hlastB bf16 (node = wave) ---
  {
    int nd = w, l64 = lane;
    float v[2], s = 0.f, q = 0.f;
    #pragma unroll
    for (int k = 0; k < 2; ++k) {
      v[k] = r2F[nd*132 + l64 + k*64];
      s += v[k]; q += v[k]*v[k];
    }
    #pragma unroll
    for (int off = 32; off > 0; off >>= 1) { s += __shfl_xor(s, off); q += __shfl_xor(q, off); }
    float mu = s*(1.f/128.f), var = q*(1.f/128.f) - mu*mu, rs = rsqrtf(var + 1e-5f);
    #pragma unroll
    for (int k = 0; k < 2; ++k) {
      int c = l64 + k*64;
      hlastB[nd*136 + c] = f2b((v[k] - mu)*rs*l2gf[c] + l2bf[c]);
    }
  }
  __syncthreads();

  // --- phase 11: xl1 = hlast @ gW1 via MFMA (nt = w); s1/d1; globals out ---
  {
    bs8 af[4];
    #pragma unroll
    for (int kk = 0; kk < 4; ++kk)
      af[kk] = *(const bs8*)&hlastB[ar8*136 + kk*32 + akg*8];
    const bs8* bq = (const bs8*)gW1F + w*256 + lane;
    fvec4 a4 = {0.f, 0.f, 0.f, 0.f};
    #pragma unroll
    for (int kk = 0; kk < 4; ++kk)
      a4 = mfma16(af[kk], bq[kk*64], a4);
    if (lane < 32) {
      int drow = akg*4, dc = arow;
      int c = w*16 + dc;
      #pragma unroll
      for (int reg = 0; reg < 4; ++reg)
        xlF[(drow + reg)*128 + c] = a4[reg];
    }
  }
  __syncthreads();
  {
    // xl1 write: 2 bf16 per thread packed as uint (coalesced 2 KB/wave-pair)
    float v0 = xlF[tid*2], v1 = xlF[tid*2 + 1];
    unsigned int pk = (unsigned int)f2b(v0) | ((unsigned int)f2b(v1) << 16);
    ((unsigned int*)(xl1B + (size_t)m0*HD))[tid] = pk;
    // s1/d1: node = wave; lane owns cols c = l64 + k*64 (k<2);
    // 32-lane-group reduce -> lanes 0/32 hold per-head sums.
    int nd = w, l64 = lane;
    float pa[2], pb[2];
    #pragma unroll
    for (int k = 0; k < 2; ++k) {
      int c = l64 + k*64;
      float xv = xlF[nd*128 + c];
      pa[k] = xv * asrc[c];
      pb[k] = xv * adrc[c];
    }
    #pragma unroll
    for (int off = 16; off > 0; off >>= 1) {
      #pragma unroll
      for (int k = 0; k < 2; ++k) {
        pa[k] += __shfl_xor(pa[k], off);
        pb[k] += __shfl_xor(pb[k], off);
      }
    }
    if ((l64 & 31) == 0) {
      int m = m0 + nd;
      int hh = l64 >> 5;          // 0 or 1
      s1[m*NH + hh]     = pa[0];  // heads 0/1 from k=0 halves
      d1[m*NH + hh]     = pb[0];
      s1[m*NH + 2 + hh] = pa[1];  // heads 2/3 from k=1 halves
      d1[m*NH + 2 + hh] = pb[1];
    }
  }
}

// ---------------- CSR build (batch-shared; cnt zeroed by k_prep) ------------
__global__ __launch_bounds__(256) void k_hist(const int* __restrict__ e1,
                                              int* __restrict__ cnt)
{
  int i = blockIdx.x * 256 + threadIdx.x;
  if (i < EE) atomicAdd(&cnt[e1[i]], 1);
}

__global__ __launch_bounds__(1024) void k_scan(const int* __restrict__ cnt,
                                               int* __restrict__ row_ptr,
                                               int* __restrict__ cur)
{
  __shared__ int sm[1024];
  int tid = threadIdx.x;
  int base = tid * 10;
  int loc[10];
  int s = 0;
  #pragma unroll
  for (int k = 0; k < 10; ++k) {
    int idx = base + k;
    int v = (idx < NN) ? cnt[idx] : 0;
    loc[k] = s;
    s += v;
  }
  sm[tid] = s;
  __syncthreads();
  for (int off = 1; off < 1024; off <<= 1) {
    int t = (tid >= off) ? sm[tid - off] : 0;
    __syncthreads();
    sm[tid] += t;
    __syncthreads();
  }
  int segbase = sm[tid] - s;
  #pragma unroll
  for (int k = 0; k < 10; ++k) {
    int idx = base + k;
    if (idx < NN) { int o = segbase + loc[k]; row_ptr[idx] = o; cur[idx] = o; }
  }
  if (tid == 1023) row_ptr[NN] = sm[1023];
}

__global__ __launch_bounds__(256) void k_scatter(const int* __restrict__ e0,
                                                 const int* __restrict__ e1,
                                                 int* __restrict__ cur,
                                                 int* __restrict__ ssrc)
{
  int i = blockIdx.x * 256 + threadIdx.x;
  if (i >= EE) return;
  int pos = atomicAdd(&cur[e1[i]], 1);
  ssrc[pos] = e0[i];
}

// ---------------- GAT1 gather + GAT2 pre (1 node/wave, 64 thr) --------------
__global__ __launch_bounds__(64) void k_g1(
    const int* __restrict__ row_ptr, const int* __restrict__ ssrc,
    const unsigned short* __restrict__ xlB,
    const float* __restrict__ s1, const float* __restrict__ d1,
    const float* __restrict__ gb1, const float* __restrict__ gW2,
    const float* __restrict__ asr2, const float* __restrict__ adr2,
    unsigned short* __restrict__ xl2B, float* __restrict__ s2, float* __restrict__ d2)
{
  __shared__ float g1s[HD];
  int j = threadIdx.x, m = blockIdx.x, h = j >> 4;   // ch 2j -> head (2j)>>5 = j>>4
  int b = m / NN, n = m - b * NN, boff = b * NN;
  float dh = d1[m*NH + h];
  int r0 = row_ptr[n], r1 = row_ptr[n+1];
  float acc0 = 0.f, acc1 = 0.f, dsum = 0.f;
  int e = r0;
  for (; e + 4 <= r1; e += 4) {
    int sa = ssrc[e]   + boff, sb = ssrc[e+1] + boff;
    int sc = ssrc[e+2] + boff, sd = ssrc[e+3] + boff;
    float ka = s1[sa*NH + h], kb = s1[sb*NH + h];
    float kc = s1[sc*NH + h], kd = s1[sd*NH + h];
    unsigned int ua = *(const unsigned int*)&xlB[(size_t)sa*HD + 2*j];
    unsigned int ub = *(const unsigned int*)&xlB[(size_t)sb*HD + 2*j];
    unsigned int uc = *(const unsigned int*)&xlB[(size_t)sc*HD + 2*j];
    unsigned int ud = *(const unsigned int*)&xlB[(size_t)sd*HD + 2*j];
    float eva = expf(lrelu(ka + dh));
    float evb = expf(lrelu(kb + dh));
    float evc = expf(lrelu(kc + dh));
    float evd = expf(lrelu(kd + dh));
    float lo, hi;
    up2(ua, lo, hi); acc0 += eva * lo; acc1 += eva * hi;
    up2(ub, lo, hi); acc0 += evb * lo; acc1 += evb * hi;
    up2(uc, lo, hi); acc0 += evc * lo; acc1 += evc * hi;
    up2(ud, lo, hi); acc0 += evd * lo; acc1 += evd * hi;
    dsum += (eva + evb) + (evc + evd);
  }
  for (; e < r1; ++e) {
    int sa = ssrc[e] + boff;
    float ev = expf(lrelu(s1[sa*NH + h] + dh));
    unsigned int u = *(const unsigned int*)&xlB[(size_t)sa*HD + 2*j];
    float lo, hi; up2(u, lo, hi);
    acc0 += ev * lo; acc1 += ev * hi;
    dsum += ev;
  }
  {
    float es = expf(lrelu(s1[m*NH + h] + dh));       // self loop
    unsigned int u = *(const unsigned int*)&xlB[(size_t)m*HD + 2*j];
    float lo, hi; up2(u, lo, hi);
    acc0 += es * lo; acc1 += es * hi;
    dsum += es;
  }
  float inv = 1.f / (dsum + 1e-16f);
  float v0 = acc0 * inv + gb1[2*j];
  float v1 = acc1 * inv + gb1[2*j + 1];
  g1s[2*j]     = v0 > 0.f ? v0 : expm1f(v0);         // ELU
  g1s[2*j + 1] = v1 > 0.f ? v1 : expm1f(v1);
  __syncthreads();
  // GAT2 pre: xl2 = g1 @ gW2 (all 64 lanes), scores fp32 pre-rounding
  float a = 0.f;
  for (int i = 0; i < HD; ++i) a += g1s[i] * gW2[i*GO + j];
  xl2B[(size_t)m*GO + j] = f2b(a);
  float pa = a * asr2[j], pb = a * adr2[j];
  #pragma unroll
  for (int off = 32; off > 0; off >>= 1) { pa += __shfl_xor(pa, off); pb += __shfl_xor(pb, off); }
  if (j == 0) { s2[m] = pa; d2[m] = pb; }
}

// ---------------- GAT2 gather + output projection (1 node/wave) -------------
__global__ __launch_bounds__(64) void k_g2(
    const int* __restrict__ row_ptr, const int* __restrict__ ssrc,
    const unsigned short* __restrict__ xl2B,
    const float* __restrict__ s2, const float* __restrict__ d2,
    const float* __restrict__ gb2, const float* __restrict__ oW, const float* __restrict__ ob,
    float* __restrict__ y)
{
  __shared__ float g2s[GO];
  int j = threadIdx.x, m = blockIdx.x;
  int b = m / NN, n = m - b * NN, boff = b * NN;
  float d2m = d2[m];
  int r0 = row_ptr[n], r1 = row_ptr[n+1];
  float acc = 0.f, dsum = 0.f;
  int e = r0;
  for (; e + 4 <= r1; e += 4) {
    int sa = ssrc[e]   + boff, sb = ssrc[e+1] + boff;
    int sc = ssrc[e+2] + boff, sd = ssrc[e+3] + boff;
    float ka = s2[sa], kb = s2[sb], kc = s2[sc], kd = s2[sd];
    unsigned short xa = xl2B[(size_t)sa*GO + j];
    unsigned short xb = xl2B[(size_t)sb*GO + j];
    unsigned short xc2 = xl2B[(size_t)sc*GO + j];
    unsigned short xd = xl2B[(size_t)sd*GO + j];
    float eva = expf(lrelu(ka + d2m));
    float evb = expf(lrelu(kb + d2m));
    float evc = expf(lrelu(kc + d2m));
    float evd = expf(lrelu(kd + d2m));
    acc  += (eva * b2f(xa) + evb * b2f(xb)) + (evc * b2f(xc2) + evd * b2f(xd));
    dsum += (eva + evb) + (evc + evd);
  }
  for (; e < r1; ++e) {
    int sa = ssrc[e] + boff;
    float ev = expf(lrelu(s2[sa] + d2m));
    acc  += ev * b2f(xl2B[(size_t)sa*GO + j]);
    dsum += ev;
  }
  float es = expf(lrelu(s2[m] + d2m));
  acc  += es * b2f(xl2B[(size_t)m*GO + j]);
  dsum += es;
  g2s[j] = acc / (dsum + 1e-16f) + gb2[j];
  __syncthreads();
  if (j < HR) {
    float a = ob[j];
    #pragma unroll
    for (int o2 = 0; o2 < GO; ++o2) a += g2s[o2] * oW[o2*HR + j];
    y[((size_t)b*HR + j)*NN + n] = a;
  }
}

// ---------------- launch ----------------------------------------------------
extern "C" void kernel_launch(void* const* d_in, const int* in_sizes, int n_in,
                              void* d_out, int out_size, void* d_ws, size_t ws_size,
                              hipStream_t stream)
{
  const int* ei = (const int*)d_in[2];
  const int* e0 = ei;
  const int* e1 = ei + EE;

  float* ws = (float*)d_ws;
  unsigned short* xl1B = (unsigned short*)ws;             // 40000*128 bf16
  unsigned short* xl2B = (unsigned short*)(ws + 2560000); // 40000*64 bf16
  float* ovl = ws + 3840000;          // weights region
  float* s1  = ws + 4200000;          // 40000*4
  float* d1  = ws + 4360000;          // 40000*4
  float* s2  = ws + 4520000;          // 40000
  float* d2  = ws + 4560000;          // 40000
  // CSR region (dedicated; cnt zeroed inside k_prep)
  int* cnt     = (int*)(ws + 4600000);   // 10000
  int* row_ptr = cnt + 16384;            // 10001
  int* cur     = cnt + 32768;            // 10000
  int* ssrc    = cnt + 49152;            // 160000

  // Weight buffers (fragment order) in ovl.
  unsigned short* Mu    = (unsigned short*)ovl;          // 65536 bf16 frags
  unsigned short* Pw    = Mu + 65536;                    // 65536
  unsigned short* W1F   = Mu + 131072;                   // 32768
  unsigned short* W2F   = Mu + 163840;                   // 32768
  unsigned short* encWF = Mu + 196608;                   // 4096
  unsigned short* gW1F  = Mu + 200704;                   // 16384
  float* encBf = (float*)(Mu + 217088);
  float* fb1f  = encBf + 128;
  float* fb2f  = fb1f + 256;
  float* l1gf  = fb2f + 128;
  float* l1bf  = l1gf + 128;
  float* l2gf  = l1bf + 128;
  float* l2bf  = l2gf + 128;

  k_prep<<<892, 256, 0, stream>>>(
      (const float*)d_in[5], (const float*)d_in[6], (const float*)d_in[7], (const float*)d_in[8],
      (const float*)d_in[3], (const float*)d_in[4], (const float*)d_in[11], (const float*)d_in[12],
      (const float*)d_in[13], (const float*)d_in[14], (const float*)d_in[9], (const float*)d_in[10],
      (const float*)d_in[15], (const float*)d_in[16], (const float*)d_in[17],
      Mu, Pw, W1F, W2F, encWF, gW1F,
      encBf, fb1f, fb2f, l1gf, l1bf, l2gf, l2bf, cnt);

  k_hist<<<(EE + 255)/256, 256, 0, stream>>>(e1, cnt);
  k_scan<<<1, 1024, 0, stream>>>(cnt, row_ptr, cur);
  k_scatter<<<(EE + 255)/256, 256, 0, stream>>>(e0, e1, cur, ssrc);

  k_xform<<<MM/8, 512, 0, stream>>>(
      (const float*)d_in[0], (const float*)d_in[1],
      Mu, Pw, W1F, W2F, encWF, gW1F,
      encBf, fb1f, fb2f, l1gf, l1bf, l2gf, l2bf,
      (const float*)d_in[18], (const float*)d_in[19],
      xl1B, s1, d1);

  k_g1<<<MM, 64, 0, stream>>>(row_ptr, ssrc, xl1B, s1, d1,
      (const float*)d_in[20], (const float*)d_in[21],
      (const float*)d_in[22], (const float*)d_in[23],
      xl2B, s2, d2);

  k_g2<<<MM, 64, 0, stream>>>(row_ptr, ssrc, xl2B, s2, d2,
      (const float*)d_in[24], (const float*)d_in[25], (const float*)d_in[26],
      (float*)d_out);
}

// Round 16
// 239.644 us; speedup vs baseline: 1.0922x; 1.0922x over previous
//
#include <hip/hip_runtime.h>
#include <hip/hip_bf16.h>

#define DEV static __device__ __forceinline__

constexpr int BB = 4;        // batches
constexpr int TT = 12;       // timesteps
constexpr int NN = 10000;    // nodes per batch
constexpr int FD = 16;       // input features (8+8)
constexpr int HD = 128;      // hidden
constexpr int NH = 4;        // attn heads
constexpr int DH = 32;       // head dim
constexpr int FF = 256;      // ffn hidden
constexpr int GO = 64;       // gat2 out
constexpr int HR = 24;       // horizon
constexpr int EE = 160000;   // edges per batch
constexpr int MM = BB * NN;  // total nodes

typedef unsigned short bvec8 __attribute__((ext_vector_type(8)));
typedef unsigned short usvec4 __attribute__((ext_vector_type(4)));
typedef float fvec4 __attribute__((ext_vector_type(4)));
typedef short bs8 __attribute__((ext_vector_type(8)));      // MFMA bf16 frag (4 VGPR)

DEV float lrelu(float x) { return x >= 0.f ? x : 0.2f * x; }

DEV float b2f(unsigned short u) {
  union { unsigned int i; float f; } x; x.i = ((unsigned int)u) << 16; return x.f;
}
DEV unsigned short f2b(float f) {
  union { float f; unsigned int i; } x; x.f = f;
  unsigned int r = x.i + 0x7FFFu + ((x.i >> 16) & 1u);
  return (unsigned short)(r >> 16);
}
DEV void up2(unsigned int u, float& lo, float& hi) {
  union { unsigned int i; float f; } a, b;
  a.i = u << 16; b.i = u & 0xFFFF0000u;
  lo = a.f; hi = b.f;
}

DEV fvec4 mfma16(bs8 a, bs8 b, fvec4 c) {
  return __builtin_amdgcn_mfma_f32_16x16x32_bf16(a, b, c, 0, 0, 0);
}

// ---------------- prep: fold + re-layout ALL transformer weights (fp32 in) --
// Also zeroes the CSR histogram (tail blocks) -- saves a launch.
// MFMA B-fragment order: frag idx = ((nt*nK + kk)*64 + lane), element e:
//   B[k][n] with k = kk*32 + (lane>>4)*8 + e, n = nt*16 + (lane&15).
__global__ __launch_bounds__(256) void k_prep(
    const float* __restrict__ Wq, const float* __restrict__ Wk,
    const float* __restrict__ Wv, const float* __restrict__ Wo,
    const float* __restrict__ encW, const float* __restrict__ encB,
    const float* __restrict__ W1, const float* __restrict__ fb1,
    const float* __restrict__ W2, const float* __restrict__ fb2,
    const float* __restrict__ l1g, const float* __restrict__ l1b,
    const float* __restrict__ l2g, const float* __restrict__ l2b,
    const float* __restrict__ gW1,
    unsigned short* __restrict__ Mu, unsigned short* __restrict__ Pw,
    unsigned short* __restrict__ W1F, unsigned short* __restrict__ W2F,
    unsigned short* __restrict__ encWF, unsigned short* __restrict__ gW1F,
    float* __restrict__ encBf, float* __restrict__ fb1f, float* __restrict__ fb2f,
    float* __restrict__ l1gf, float* __restrict__ l1bf,
    float* __restrict__ l2gf, float* __restrict__ l2bf,
    int* __restrict__ cnt)
{
  int idx = blockIdx.x * 256 + threadIdx.x;      // 892*256 = 228352
  if (idx < 65536) {
    int e = idx & 7, lane = (idx >> 3) & 63, kk = (idx >> 9) & 3, nt = idx >> 11;
    int i = kk*32 + (lane >> 4)*8 + e;
    int q = nt*16 + (lane & 15);
    int h = q >> 7, c = q & 127;
    float a = 0.f;
    #pragma unroll 8
    for (int d = 0; d < DH; ++d)
      a += Wq[i*HD + h*DH + d] * Wk[c*HD + h*DH + d];
    Mu[idx] = f2b(a);
  } else if (idx < 131072) {
    int g2 = idx - 65536;
    int e = g2 & 7, lane = (g2 >> 3) & 63, kk = (g2 >> 9) & 15, nt = g2 >> 13;
    int q = kk*32 + (lane >> 4)*8 + e;
    int j = nt*16 + (lane & 15);
    int h = q >> 7, i = q & 127;
    float a = 0.f;
    #pragma unroll 8
    for (int d = 0; d < DH; ++d)
      a += Wv[i*HD + h*DH + d] * Wo[(h*DH + d)*HD + j];
    Pw[g2] = f2b(a);
  } else if (idx < 163840) {
    int g = idx - 131072;
    int e = g & 7, lane = (g >> 3) & 63, kk = (g >> 9) & 3, nt = g >> 11;
    int k = kk*32 + (lane >> 4)*8 + e;
    int n = nt*16 + (lane & 15);
    W1F[g] = f2b(W1[k*FF + n]);
  } else if (idx < 196608) {
    int g = idx - 163840;
    int e = g & 7, lane = (g >> 3) & 63, kk = (g >> 9) & 7, nt = g >> 12;
    int k = kk*32 + (lane >> 4)*8 + e;
    int n = nt*16 + (lane & 15);
    W2F[g] = f2b(W2[k*HD + n]);
  } else if (idx < 200704) {
    int g = idx - 196608;
    int e = g & 7, lane = (g >> 3) & 63, nt = g >> 9;
    int k = (lane >> 4)*8 + e;
    int n = nt*16 + (lane & 15);
    encWF[g] = (k < FD) ? f2b(encW[k*HD + n]) : (unsigned short)0;
  } else if (idx < 217088) {
    int g = idx - 200704;
    int e = g & 7, lane = (g >> 3) & 63, kk = (g >> 9) & 3, nt = g >> 11;
    int k = kk*32 + (lane >> 4)*8 + e;
    int n = nt*16 + (lane & 15);
    gW1F[g] = f2b(gW1[k*HD + n]);
  } else if (idx < 217216) { int t = idx - 217088; encBf[t] = encB[t]; }
  else if (idx < 217472)   { int t = idx - 217216; fb1f[t] = fb1[t]; }
  else if (idx < 217600)   { int t = idx - 217472; fb2f[t] = fb2[t]; }
  else if (idx < 217728)   { int t = idx - 217600; l1gf[t] = l1g[t]; }
  else if (idx < 217856)   { int t = idx - 217728; l1bf[t] = l1b[t]; }
  else if (idx < 217984)   { int t = idx - 217856; l2gf[t] = l2g[t]; }
  else if (idx < 218112)   { int t = idx - 217984; l2bf[t] = l2b[t]; }
  else { int t = idx - 218112; if (t < NN) cnt[t] = 0; }
}

// ---------------- fused transformer + GAT1-pre (8 nodes/block, 256 thr) -----
// LDS 38912 B -> 4 blocks/CU (16 waves). A-frag rows beyond the real data
// feed only DISCARDED D rows (aliased in-bounds). All A-frag row strides
// are 16B multiples (round-8 lesson). 256-thr config is the verified best
// (round 14: 140 us; 512-thr round 15 regressed to 155 us, occupancy flat).
__global__ __launch_bounds__(256) void k_xform(
    const float* __restrict__ xh, const float* __restrict__ xc,
    const unsigned short* __restrict__ MuF, const unsigned short* __restrict__ PwF,
    const unsigned short* __restrict__ W1F, const unsigned short* __restrict__ W2F,
    const unsigned short* __restrict__ encWF, const unsigned short* __restrict__ gW1F,
    const float* __restrict__ encBf,
    const float* __restrict__ fb1f, const float* __restrict__ fb2f,
    const float* __restrict__ l1gf, const float* __restrict__ l1bf,
    const float* __restrict__ l2gf, const float* __restrict__ l2bf,
    const float* __restrict__ asrc, const float* __restrict__ adrc,
    unsigned short* __restrict__ xl1B, float* __restrict__ s1, float* __restrict__ d1)
{
  // big: hsB (ph1-5) then {r1F,h1s,h1B,f1B,r2F} (ph6-10)
  __shared__ __align__(16) char big[26112];
  __shared__ unsigned short hlastB[8*136];     // bf16 h_last (A-frags + residual)
  __shared__ float lgaw[8][NH][TT];
  __shared__ __align__(16) char regB[8704];    // xB -> usB -> wB -> xlF

  unsigned short* hsB = (unsigned short*)big;          // [(nl*12+t)][136]
  float* r1F = (float*)big;                            // [8][132] ph6-7
  float* h1s = (float*)(big + 4224);                   // [8][132] ph7-9
  unsigned short* h1B = (unsigned short*)(big + 8448); // [8][136] ph7-8
  float* r2F = (float*)(big + 8448);                   // [8][132] ph9-10 (over h1B)
  unsigned short* f1B = (unsigned short*)(big + 12672);// [8][264] ph8-9

  unsigned short* xB  = (unsigned short*)regB;         // [96][40]  ph0-1
  unsigned short* usB = (unsigned short*)regB;         // [8*4][136] ph2-3 (bf16 u)
  unsigned short* wB  = (unsigned short*)regB;         // [8][520]  ph5-6
  float* xlF = (float*)regB;                           // [8][128]  ph11

  const int tid  = threadIdx.x;
  const int w    = tid >> 6;
  const int lane = tid & 63;
  const int m0   = blockIdx.x * 8;
  const int arow = lane & 15, akg = lane >> 4;
  const int ar8  = arow & 7;                   // aliased A-row (rows 8-15 -> 0-7)

  // --- phase 0: load x -> xB bf16, rows = t*8+nl, K zero-padded 16..31 ---
  #pragma unroll
  for (int k = 0; k < 6; ++k) {
    int idx = tid + k*256;
    int f = idx & 15, rest = idx >> 4;
    int nl = rest & 7, t = rest >> 3;
    int m = m0 + nl, b = m / NN, n = m - b*NN;
    float v = (f < 8) ? xh[(((size_t)b*TT + t)*NN + n)*8 + f]
                      : xc[(((size_t)b*TT + t)*NN + n)*8 + (f - 8)];
    xB[(t*8 + nl)*40 + f] = f2b(v);
  }
  #pragma unroll
  for (int k = 0; k < 6; ++k) {
    int idx = tid + k*256;
    xB[(idx >> 4)*40 + 16 + (idx & 15)] = 0;
  }
  __syncthreads();

  // --- phase 1: encoder via MFMA (96x128 = 6 mt x 8 nt tiles) ---
  {
    const bs8* ef = (const bs8*)encWF;
    bs8 b0 = ef[(2*w + 0)*64 + lane];
    bs8 b1 = ef[(2*w + 1)*64 + lane];
    int drow = akg*4, dc = arow;
    int j0 = (2*w + 0)*16 + dc, j1 = (2*w + 1)*16 + dc;
    float eb0 = encBf[j0], eb1 = encBf[j1];
    fvec4 z4 = {0.f, 0.f, 0.f, 0.f};
    #pragma unroll
    for (int mt = 0; mt < 6; ++mt) {
      bs8 af = *(const bs8*)&xB[(mt*16 + arow)*40 + akg*8];
      fvec4 d0 = mfma16(af, b0, z4);
      fvec4 d1 = mfma16(af, b1, z4);
      #pragma unroll
      for (int reg = 0; reg < 4; ++reg) {
        int gr = mt*16 + drow + reg;
        int t = gr >> 3, nl = gr & 7;
        float v0 = d0[reg] + eb0, v1 = d1[reg] + eb1;
        unsigned short s0 = f2b(v0), s1v = f2b(v1);
        hsB[(nl*12 + t)*136 + j0] = s0;
        hsB[(nl*12 + t)*136 + j1] = s1v;
        if (t == TT-1) {
          hlastB[nl*136 + j0] = s0;
          hlastB[nl*136 + j1] = s1v;
        }
      }
    }
  }
  __syncthreads();                // xB dead

  // --- phase 2: u = h_last @ Mu via MFMA -> usB bf16 [nl*4+hd][136] ---
  {
    bs8 af[4];
    #pragma unroll
    for (int kk = 0; kk < 4; ++kk)
      af[kk] = *(const bs8*)&hlastB[ar8*136 + kk*32 + akg*8];
    const bs8* bp = (const bs8*)MuF;
    fvec4 acc[8];
    #pragma unroll
    for (int n8 = 0; n8 < 8; ++n8) {
      int nt = w*8 + n8;
      const bs8* bq = bp + nt*256 + lane;
      fvec4 a4 = {0.f, 0.f, 0.f, 0.f};
      #pragma unroll
      for (int kk = 0; kk < 4; ++kk)
        a4 = mfma16(af[kk], bq[kk*64], a4);
      acc[n8] = a4;
    }
    __syncthreads();              // xB fully read before usB overlay write
    if (lane < 32) {
      int drow = akg*4, dc = arow;
      #pragma unroll
      for (int n8 = 0; n8 < 8; ++n8) {
        int col = (w*8 + n8)*16 + dc, hd = col >> 7, c = col & 127;
        #pragma unroll
        for (int reg = 0; reg < 4; ++reg)
          usB[((drow + reg)*4 + hd)*136 + c] = f2b(acc[n8][reg]);
      }
    }
  }
  __syncthreads();

  // --- phase 3: logits via MFMA. Per node: D[t][hd] = Ht(12x128) @ u^T. ---
  {
    int ar12 = (arow < 12) ? arow : 0;
    #pragma unroll
    for (int r = 0; r < 2; ++r) {
      int nl = w*2 + r;
      const unsigned short* hb = &hsB[(nl*12 + ar12)*136 + akg*8];
      const unsigned short* ub = &usB[(nl*4 + (arow & 3))*136 + akg*8];
      fvec4 a4 = {0.f, 0.f, 0.f, 0.f};
      #pragma unroll
      for (int kk = 0; kk < 4; ++kk) {
        bs8 af = *(const bs8*)&hb[kk*32];
        bs8 bf = *(const bs8*)&ub[kk*32];
        a4 = mfma16(af, bf, a4);
      }
      if (arow < 4) {             // D col = hd
        #pragma unroll
        for (int reg = 0; reg < 4; ++reg) {
          int t = akg*4 + reg;
          if (t < TT) lgaw[nl][arow][t] = a4[reg] * 0.17677669529663687f;
        }
      }
    }
  }
  __syncthreads();

  // --- phase 4: softmax over t ---
  if (tid < 32) {
    int nl = tid >> 2, hd = tid & 3;
    float mx = -1e30f;
    #pragma unroll
    for (int t = 0; t < TT; ++t) mx = fmaxf(mx, lgaw[nl][hd][t]);
    float ex[TT], sm = 0.f;
    #pragma unroll
    for (int t = 0; t < TT; ++t) { ex[t] = expf(lgaw[nl][hd][t] - mx); sm += ex[t]; }
    float inv = 1.f / sm;
    #pragma unroll
    for (int t = 0; t < TT; ++t) lgaw[nl][hd][t] = ex[t] * inv;
  }
  __syncthreads();

  // --- phase 5: w_h = sum_t alpha*h_t -> wB bf16 (over usB) ---
  {
    int g = tid >> 7, j = tid & 127;
    #pragma unroll
    for (int r = 0; r < 4; ++r) {
      int nl = g*4 + r;
      float wacc[NH] = {0.f, 0.f, 0.f, 0.f};
      #pragma unroll
      for (int t = 0; t < TT; ++t) {
        float hv = b2f(hsB[(nl*12 + t)*136 + j]);
        #pragma unroll
        for (int hd = 0; hd < NH; ++hd) wacc[hd] += lgaw[nl][hd][t] * hv;
      }
      #pragma unroll
      for (int hd = 0; hd < NH; ++hd) wB[nl*520 + hd*128 + j] = f2b(wacc[hd]);
    }
  }
  __syncthreads();                // hsB dead after this point

  // --- phase 6: oa = w @ Pw via MFMA; r1 = h_last + oa -> r1F (over hsB) ---
  {
    fvec4 pacc0 = {0.f,0.f,0.f,0.f}, pacc1 = {0.f,0.f,0.f,0.f};
    const bs8* bp = (const bs8*)PwF;
    const bs8* bq0 = bp + (w*2 + 0)*1024 + lane;
    const bs8* bq1 = bp + (w*2 + 1)*1024 + lane;
    #pragma unroll
    for (int kk = 0; kk < 16; ++kk) {
      bs8 af = *(const bs8*)&wB[ar8*520 + kk*32 + akg*8];
      pacc0 = mfma16(af, bq0[kk*64], pacc0);
      pacc1 = mfma16(af, bq1[kk*64], pacc1);
    }
    __syncthreads();              // wB fully read before r1F overlay write
    if (lane < 32) {
      int drow = akg*4, dc = arow;
      #pragma unroll
      for (int reg = 0; reg < 4; ++reg) {
        int nd = drow + reg;
        int c0 = (w*2 + 0)*16 + dc;
        int c1 = (w*2 + 1)*16 + dc;
        r1F[nd*132 + c0] = b2f(hlastB[nd*136 + c0]) + pacc0[reg];
        r1F[nd*132 + c1] = b2f(hlastB[nd*136 + c1]) + pacc1[reg];
      }
    }
  }
  __syncthreads();

  // --- phase 7: LN1 -> h1s fp32 + h1B bf16 ---
  {
    int nd = tid >> 5, l32 = tid & 31;
    float v[4], s = 0.f, q = 0.f;
    #pragma unroll
    for (int k = 0; k < 4; ++k) {
      v[k] = r1F[nd*132 + l32 + k*32];
      s += v[k]; q += v[k]*v[k];
    }
    #pragma unroll
    for (int off = 16; off > 0; off >>= 1) { s += __shfl_xor(s, off); q += __shfl_xor(q, off); }
    float mu = s*(1.f/128.f), var = q*(1.f/128.f) - mu*mu, rs = rsqrtf(var + 1e-5f);
    #pragma unroll
    for (int k = 0; k < 4; ++k) {
      int c = l32 + k*32;
      float hv = (v[k] - mu)*rs*l1gf[c] + l1bf[c];
      h1s[nd*132 + c] = hv;
      h1B[nd*136 + c] = f2b(hv);
    }
  }
  __syncthreads();

  // --- phase 8: FFN1 via MFMA (K=128, N=256), relu+bias fused -> f1B bf16 ---
  {
    bs8 af[4];
    #pragma unroll
    for (int kk = 0; kk < 4; ++kk)
      af[kk] = *(const bs8*)&h1B[ar8*136 + kk*32 + akg*8];
    const bs8* bp = (const bs8*)W1F;
    #pragma unroll
    for (int n4 = 0; n4 < 4; ++n4) {
      int nt = w*4 + n4;
      const bs8* bq = bp + nt*256 + lane;
      fvec4 a4 = {0.f, 0.f, 0.f, 0.f};
      #pragma unroll
      for (int kk = 0; kk < 4; ++kk)
        a4 = mfma16(af[kk], bq[kk*64], a4);
      if (lane < 32) {
        int drow = akg*4, dc = arow;
        int n = nt*16 + dc;
        float bias = fb1f[n];
        #pragma unroll
        for (int reg = 0; reg < 4; ++reg)
          f1B[(drow + reg)*264 + n] = f2b(fmaxf(a4[reg] + bias, 0.f));
      }
    }
  }
  __syncthreads();

  // --- phase 9: FFN2 via MFMA (K=256, N=128) + residual -> r2F (over h1B) ---
  {
    const bs8* bp = (const bs8*)W2F;
    #pragma unroll
    for (int n2 = 0; n2 < 2; ++n2) {
      int nt = w*2 + n2;
      const bs8* bq = bp + nt*512 + lane;
      fvec4 a4 = {0.f, 0.f, 0.f, 0.f};
      #pragma unroll
      for (int kk = 0; kk < 8; ++kk) {
        bs8 af = *(const bs8*)&f1B[ar8*264 + kk*32 + akg*8];
        a4 = mfma16(af, bq[kk*64], a4);
      }
      if (lane < 32) {
        int drow = akg*4, dc = arow;
        int c = nt*16 + dc;
        float fb2v = fb2f[c];
        #pragma unroll
        for (int reg = 0; reg < 4; ++reg) {
          int nd = drow + reg;
          r2F[nd*132 + c] = h1s[nd*132 + c] + fb2v + a4[reg];
        }
      }
    }
  }
  __syncthreads();

  // --- phase 10: LN2 -> hlastB bf16 (A-frags for GAT1 projection) ---
  {
    int nd = tid >> 5, l32 = tid & 31;
    float v[4], s = 0.f, q = 0.f;
    #pragma unroll
    for (int k = 0; k < 4; ++k) {
      v[k] = r2F[nd*132 + l32 + k*32];
      s += v[k]; q += v[k]*v[k];
    }
    #pragma unroll
    for (int off = 16; off > 0; off >>= 1) { s += __shfl_xor(s, off); q += __shfl_xor(q, off); }
    float mu = s*(1.f/128.f), var = q*(1.f/128.f) - mu*mu, rs = rsqrtf(var + 1e-5f);
    #pragma unroll
    for (int k = 0; k < 4; ++k) {
      int c = l32 + k*32;
      hlastB[nd*136 + c] = f2b((v[k] - mu)*rs*l2gf[c] + l2bf[c]);
    }
  }
  __syncthreads();

  // --- phase 11: xl1 = hlast @ gW1 via MFMA; s1/d1 reduce; globals out ---
  {
    bs8 af[4];
    #pragma unroll
    for (int kk = 0; kk < 4; ++kk)
      af[kk] = *(const bs8*)&hlastB[ar8*136 + kk*32 + akg*8];
    const bs8* bp = (const bs8*)gW1F;
    #pragma unroll
    for (int n2 = 0; n2 < 2; ++n2) {
      int nt = w*2 + n2;
      const bs8* bq = bp + nt*256 + lane;
      fvec4 a4 = {0.f, 0.f, 0.f, 0.f};
      #pragma unroll
      for (int kk = 0; kk < 4; ++kk)
        a4 = mfma16(af[kk], bq[kk*64], a4);
      if (lane < 32) {
        int drow = akg*4, dc = arow;
        int c = nt*16 + dc;
        #pragma unroll
        for (int reg = 0; reg < 4; ++reg)
          xlF[(drow + reg)*128 + c] = a4[reg];
      }
    }
  }
  __syncthreads();
  {
    // xl1 write as packed bf16 (ushort4 = 8B/lane, coalesced)
    fvec4 vv = ((const fvec4*)xlF)[tid];
    usvec4 sv;
    #pragma unroll
    for (int k = 0; k < 4; ++k) sv[k] = f2b(vv[k]);
    *(usvec4*)&xl1B[(size_t)m0*HD + tid*4] = sv;
    // s1/d1 from fp32 xlF (scores stay full precision)
    int nd = tid >> 5, l32 = tid & 31;
    float pa[4], pb[4];
    #pragma unroll
    for (int k = 0; k < 4; ++k) {
      float xv = xlF[nd*128 + l32 + k*32];
      pa[k] = xv * asrc[l32 + k*32];
      pb[k] = xv * adrc[l32 + k*32];
    }
    #pragma unroll
    for (int off = 16; off > 0; off >>= 1) {
      #pragma unroll
      for (int k = 0; k < 4; ++k) {
        pa[k] += __shfl_xor(pa[k], off);
        pb[k] += __shfl_xor(pb[k], off);
      }
    }
    if (l32 == 0) {
      int m = m0 + nd;
      #pragma unroll
      for (int k = 0; k < 4; ++k) {
        s1[m*NH + k] = pa[k];
        d1[m*NH + k] = pb[k];
      }
    }
  }
}

// ---------------- CSR build (batch-shared; cnt zeroed by k_prep) ------------
__global__ __launch_bounds__(256) void k_hist(const int* __restrict__ e1,
                                              int* __restrict__ cnt)
{
  int i = blockIdx.x * 256 + threadIdx.x;
  if (i < EE) atomicAdd(&cnt[e1[i]], 1);
}

__global__ __launch_bounds__(1024) void k_scan(const int* __restrict__ cnt,
                                               int* __restrict__ row_ptr,
                                               int* __restrict__ cur)
{
  __shared__ int sm[1024];
  int tid = threadIdx.x;
  int base = tid * 10;
  int loc[10];
  int s = 0;
  #pragma unroll
  for (int k = 0; k < 10; ++k) {
    int idx = base + k;
    int v = (idx < NN) ? cnt[idx] : 0;
    loc[k] = s;
    s += v;
  }
  sm[tid] = s;
  __syncthreads();
  for (int off = 1; off < 1024; off <<= 1) {
    int t = (tid >= off) ? sm[tid - off] : 0;
    __syncthreads();
    sm[tid] += t;
    __syncthreads();
  }
  int segbase = sm[tid] - s;
  #pragma unroll
  for (int k = 0; k < 10; ++k) {
    int idx = base + k;
    if (idx < NN) { int o = segbase + loc[k]; row_ptr[idx] = o; cur[idx] = o; }
  }
  if (tid == 1023) row_ptr[NN] = sm[1023];
}

__global__ __launch_bounds__(256) void k_scatter(const int* __restrict__ e0,
                                                 const int* __restrict__ e1,
                                                 int* __restrict__ cur,
                                                 int* __restrict__ ssrc)
{
  int i = blockIdx.x * 256 + threadIdx.x;
  if (i >= EE) return;
  int pos = atomicAdd(&cur[e1[i]], 1);
  ssrc[pos] = e0[i];
}

// ---------------- GAT1 gather + GAT2 pre (1 node/wave, 64 thr) --------------
// Single wave per node; edge loop unrolled x4 for memory-level parallelism.
__global__ __launch_bounds__(64) void k_g1(
    const int* __restrict__ row_ptr, const int* __restrict__ ssrc,
    const unsigned short* __restrict__ xlB,
    const float* __restrict__ s1, const float* __restrict__ d1,
    const float* __restrict__ gb1, const float* __restrict__ gW2,
    const float* __restrict__ asr2, const float* __restrict__ adr2,
    unsigned short* __restrict__ xl2B, float* __restrict__ s2, float* __restrict__ d2)
{
  __shared__ float g1s[HD];
  int j = threadIdx.x, m = blockIdx.x, h = j >> 4;   // ch 2j -> head (2j)>>5 = j>>4
  int b = m / NN, n = m - b * NN, boff = b * NN;
  float dh = d1[m*NH + h];
  int r0 = row_ptr[n], r1 = row_ptr[n+1];
  float acc0 = 0.f, acc1 = 0.f, dsum = 0.f;
  int e = r0;
  for (; e + 4 <= r1; e += 4) {
    int sa = ssrc[e]   + boff, sb = ssrc[e+1] + boff;
    int sc = ssrc[e+2] + boff, sd = ssrc[e+3] + boff;
    float ka = s1[sa*NH + h], kb = s1[sb*NH + h];
    float kc = s1[sc*NH + h], kd = s1[sd*NH + h];
    unsigned int ua = *(const unsigned int*)&xlB[(size_t)sa*HD + 2*j];
    unsigned int ub = *(const unsigned int*)&xlB[(size_t)sb*HD + 2*j];
    unsigned int uc = *(const unsigned int*)&xlB[(size_t)sc*HD + 2*j];
    unsigned int ud = *(const unsigned int*)&xlB[(size_t)sd*HD + 2*j];
    float eva = expf(lrelu(ka + dh));
    float evb = expf(lrelu(kb + dh));
    float evc = expf(lrelu(kc + dh));
    float evd = expf(lrelu(kd + dh));
    float lo, hi;
    up2(ua, lo, hi); acc0 += eva * lo; acc1 += eva * hi;
    up2(ub, lo, hi); acc0 += evb * lo; acc1 += evb * hi;
    up2(uc, lo, hi); acc0 += evc * lo; acc1 += evc * hi;
    up2(ud, lo, hi); acc0 += evd * lo; acc1 += evd * hi;
    dsum += (eva + evb) + (evc + evd);
  }
  for (; e < r1; ++e) {
    int sa = ssrc[e] + boff;
    float ev = expf(lrelu(s1[sa*NH + h] + dh));
    unsigned int u = *(const unsigned int*)&xlB[(size_t)sa*HD + 2*j];
    float lo, hi; up2(u, lo, hi);
    acc0 += ev * lo; acc1 += ev * hi;
    dsum += ev;
  }
  {
    float es = expf(lrelu(s1[m*NH + h] + dh));       // self loop
    unsigned int u = *(const unsigned int*)&xlB[(size_t)m*HD + 2*j];
    float lo, hi; up2(u, lo, hi);
    acc0 += es * lo; acc1 += es * hi;
    dsum += es;
  }
  float inv = 1.f / (dsum + 1e-16f);
  float v0 = acc0 * inv + gb1[2*j];
  float v1 = acc1 * inv + gb1[2*j + 1];
  g1s[2*j]     = v0 > 0.f ? v0 : expm1f(v0);         // ELU
  g1s[2*j + 1] = v1 > 0.f ? v1 : expm1f(v1);
  __syncthreads();
  // GAT2 pre: xl2 = g1 @ gW2 (all 64 lanes), scores fp32 pre-rounding
  float a = 0.f;
  for (int i = 0; i < HD; ++i) a += g1s[i] * gW2[i*GO + j];
  xl2B[(size_t)m*GO + j] = f2b(a);
  float pa = a * asr2[j], pb = a * adr2[j];
  #pragma unroll
  for (int off = 32; off > 0; off >>= 1) { pa += __shfl_xor(pa, off); pb += __shfl_xor(pb, off); }
  if (j == 0) { s2[m] = pa; d2[m] = pb; }
}

// ---------------- GAT2 gather + output projection (1 node/wave) -------------
__global__ __launch_bounds__(64) void k_g2(
    const int* __restrict__ row_ptr, const int* __restrict__ ssrc,
    const unsigned short* __restrict__ xl2B,
    const float* __restrict__ s2, const float* __restrict__ d2,
    const float* __restrict__ gb2, const float* __restrict__ oW, const float* __restrict__ ob,
    float* __restrict__ y)
{
  __shared__ float g2s[GO];
  int j = threadIdx.x, m = blockIdx.x;
  int b = m / NN, n = m - b * NN, boff = b * NN;
  float d2m = d2[m];
  int r0 = row_ptr[n], r1 = row_ptr[n+1];
  float acc = 0.f, dsum = 0.f;
  int e = r0;
  for (; e + 4 <= r1; e += 4) {
    int sa = ssrc[e]   + boff, sb = ssrc[e+1] + boff;
    int sc = ssrc[e+2] + boff, sd = ssrc[e+3] + boff;
    float ka = s2[sa], kb = s2[sb], kc = s2[sc], kd = s2[sd];
    unsigned short xa = xl2B[(size_t)sa*GO + j];
    unsigned short xb = xl2B[(size_t)sb*GO + j];
    unsigned short xc2 = xl2B[(size_t)sc*GO + j];
    unsigned short xd = xl2B[(size_t)sd*GO + j];
    float eva = expf(lrelu(ka + d2m));
    float evb = expf(lrelu(kb + d2m));
    float evc = expf(lrelu(kc + d2m));
    float evd = expf(lrelu(kd + d2m));
    acc  += (eva * b2f(xa) + evb * b2f(xb)) + (evc * b2f(xc2) + evd * b2f(xd));
    dsum += (eva + evb) + (evc + evd);
  }
  for (; e < r1; ++e) {
    int sa = ssrc[e] + boff;
    float ev = expf(lrelu(s2[sa] + d2m));
    acc  += ev * b2f(xl2B[(size_t)sa*GO + j]);
    dsum += ev;
  }
  float es = expf(lrelu(s2[m] + d2m));
  acc  += es * b2f(xl2B[(size_t)m*GO + j]);
  dsum += es;
  g2s[j] = acc / (dsum + 1e-16f) + gb2[j];
  __syncthreads();
  if (j < HR) {
    float a = ob[j];
    #pragma unroll
    for (int o2 = 0; o2 < GO; ++o2) a += g2s[o2] * oW[o2*HR + j];
    y[((size_t)b*HR + j)*NN + n] = a;
  }
}

// ---------------- launch ----------------------------------------------------
extern "C" void kernel_launch(void* const* d_in, const int* in_sizes, int n_in,
                              void* d_out, int out_size, void* d_ws, size_t ws_size,
                              hipStream_t stream)
{
  const int* ei = (const int*)d_in[2];
  const int* e0 = ei;
  const int* e1 = ei + EE;

  float* ws = (float*)d_ws;
  unsigned short* xl1B = (unsigned short*)ws;             // 40000*128 bf16
  unsigned short* xl2B = (unsigned short*)(ws + 2560000); // 40000*64 bf16
  float* ovl = ws + 3840000;          // weights region
  float* s1  = ws + 4200000;          // 40000*4
  float* d1  = ws + 4360000;          // 40000*4
  float* s2  = ws + 4520000;          // 40000
  float* d2  = ws + 4560000;          // 40000
  // CSR region (dedicated; cnt zeroed inside k_prep)
  int* cnt     = (int*)(ws + 4600000);   // 10000
  int* row_ptr = cnt + 16384;            // 10001
  int* cur     = cnt + 32768;            // 10000
  int* ssrc    = cnt + 49152;            // 160000

  // Weight buffers (fragment order) in ovl.
  unsigned short* Mu    = (unsigned short*)ovl;          // 65536 bf16 frags
  unsigned short* Pw    = Mu + 65536;                    // 65536
  unsigned short* W1F   = Mu + 131072;                   // 32768
  unsigned short* W2F   = Mu + 163840;                   // 32768
  unsigned short* encWF = Mu + 196608;                   // 4096
  unsigned short* gW1F  = Mu + 200704;                   // 16384
  float* encBf = (float*)(Mu + 217088);
  float* fb1f  = encBf + 128;
  float* fb2f  = fb1f + 256;
  float* l1gf  = fb2f + 128;
  float* l1bf  = l1gf + 128;
  float* l2gf  = l1bf + 128;
  float* l2bf  = l2gf + 128;

  k_prep<<<892, 256, 0, stream>>>(
      (const float*)d_in[5], (const float*)d_in[6], (const float*)d_in[7], (const float*)d_in[8],
      (const float*)d_in[3], (const float*)d_in[4], (const float*)d_in[11], (const float*)d_in[12],
      (const float*)d_in[13], (const float*)d_in[14], (const float*)d_in[9], (const float*)d_in[10],
      (const float*)d_in[15], (const float*)d_in[16], (const float*)d_in[17],
      Mu, Pw, W1F, W2F, encWF, gW1F,
      encBf, fb1f, fb2f, l1gf, l1bf, l2gf, l2bf, cnt);

  k_hist<<<(EE + 255)/256, 256, 0, stream>>>(e1, cnt);
  k_scan<<<1, 1024, 0, stream>>>(cnt, row_ptr, cur);
  k_scatter<<<(EE + 255)/256, 256, 0, stream>>>(e0, e1, cur, ssrc);

  k_xform<<<MM/8, 256, 0, stream>>>(
      (const float*)d_in[0], (const float*)d_in[1],
      Mu, Pw, W1F, W2F, encWF, gW1F,
      encBf, fb1f, fb2f, l1gf, l1bf, l2gf, l2bf,
      (const float*)d_in[18], (const float*)d_in[19],
      xl1B, s1, d1);

  k_g1<<<MM, 64, 0, stream>>>(row_ptr, ssrc, xl1B, s1, d1,
      (const float*)d_in[20], (const float*)d_in[21],
      (const float*)d_in[22], (const float*)d_in[23],
      xl2B, s2, d2);

  k_g2<<<MM, 64, 0, stream>>>(row_ptr, ssrc, xl2B, s2, d2,
      (const float*)d_in[24], (const float*)d_in[25], (const float*)d_in[26],
      (float*)d_out);
}